// Round 2
// baseline (1986.308 us; speedup 1.0000x reference)
//
#include <hip/hip_runtime.h>
#include <math.h>

#define N_NODES 8192
#define N_EDGES 32768
#define HID 8
#define FEAT 11          // HID + 3
#define E4   (N_EDGES/4) // 8192 float4 per matrix row (power of 2)
#define UNROLL 4         // independent float4 loads per matrix per outer iter

// Scan BOTH dense one-hot incidence matrices [N_NODES, N_EDGES] (row-major)
// and recover the per-column node index. Exactly one nonzero per column, so
// the plain (non-atomic) store is race-free.
//
// Key structure: batch UNROLL independent grid-strided float4 loads from each
// matrix into registers BEFORE any data-dependent compare, so the wave keeps
// 2*UNROLL loads in flight (avoids the load->vmcnt(0)->test serialization of
// a naive grid-stride loop). Every load is coalesced across the wave.
__global__ void scan_both(const float4* __restrict__ Ri4,
                          const float4* __restrict__ Ro4,
                          int* __restrict__ idx_i,
                          int* __restrict__ idx_o) {
    const long total4   = (long)N_NODES * E4;            // 2^26
    const long nthreads = (long)gridDim.x * blockDim.x;  // 2^20
    const long j0 = (long)blockIdx.x * blockDim.x + threadIdx.x;

    // total4 (2^26) is an exact multiple of nthreads*UNROLL (2^22): no tail.
    for (long base = j0; base < total4; base += nthreads * UNROLL) {
        float4 vi[UNROLL], vo[UNROLL];
#pragma unroll
        for (int k = 0; k < UNROLL; ++k) {
            long j = base + (long)k * nthreads;
            vi[k] = Ri4[j];
            vo[k] = Ro4[j];
        }
#pragma unroll
        for (int k = 0; k < UNROLL; ++k) {
            long j = base + (long)k * nthreads;
            int n = (int)(j >> 13);              // row = j / E4 (E4 = 2^13)
            int e = (((int)j) & (E4 - 1)) << 2;  // col = (j % E4) * 4
            if (vi[k].x != 0.0f) idx_i[e + 0] = n;
            if (vi[k].y != 0.0f) idx_i[e + 1] = n;
            if (vi[k].z != 0.0f) idx_i[e + 2] = n;
            if (vi[k].w != 0.0f) idx_i[e + 3] = n;
            if (vo[k].x != 0.0f) idx_o[e + 0] = n;
            if (vo[k].y != 0.0f) idx_o[e + 1] = n;
            if (vo[k].z != 0.0f) idx_o[e + 2] = n;
            if (vo[k].w != 0.0f) idx_o[e + 3] = n;
        }
    }
}

// Per-edge: gather both endpoint feature rows, run the 2-layer MLP.
// B = [X[idx_o[e]], X[idx_i[e]]] (bo first, bi second, matching the
// reference's concatenate([bo, bi])), h = tanh(B @ W1 + b1),
// out = sigmoid(h @ W2 + b2).
__global__ void edge_mlp(const float* __restrict__ X,
                         const int*   __restrict__ idx_i,
                         const int*   __restrict__ idx_o,
                         const float* __restrict__ W1,  // [2*FEAT, HID]
                         const float* __restrict__ b1,  // [HID]
                         const float* __restrict__ W2,  // [HID]
                         const float* __restrict__ b2,  // [1]
                         float* __restrict__ out) {
    int e = blockIdx.x * blockDim.x + threadIdx.x;
    if (e >= N_EDGES) return;

    const float* xo = X + (long)idx_o[e] * FEAT;
    const float* xi = X + (long)idx_i[e] * FEAT;

    float h[HID];
#pragma unroll
    for (int j = 0; j < HID; ++j) h[j] = b1[j];

#pragma unroll
    for (int f = 0; f < FEAT; ++f) {
        float vo = xo[f];
        float vi = xi[f];
#pragma unroll
        for (int j = 0; j < HID; ++j) {
            h[j] += vo * W1[f * HID + j] + vi * W1[(FEAT + f) * HID + j];
        }
    }

    float acc = b2[0];
#pragma unroll
    for (int j = 0; j < HID; ++j) acc += tanhf(h[j]) * W2[j];

    out[e] = 1.0f / (1.0f + expf(-acc));
}

extern "C" void kernel_launch(void* const* d_in, const int* in_sizes, int n_in,
                              void* d_out, int out_size, void* d_ws, size_t ws_size,
                              hipStream_t stream) {
    const float* X  = (const float*)d_in[0];  // [8192, 11]
    const float* Ri = (const float*)d_in[1];  // [8192, 32768]
    const float* Ro = (const float*)d_in[2];  // [8192, 32768]
    const float* W1 = (const float*)d_in[3];  // [22, 8]
    const float* b1 = (const float*)d_in[4];  // [8]
    const float* W2 = (const float*)d_in[5];  // [8]
    const float* b2 = (const float*)d_in[6];  // [1]
    float* out = (float*)d_out;               // [32768]

    int* idx_i = (int*)d_ws;           // 32768 ints (every slot written by scan)
    int* idx_o = idx_i + N_EDGES;      // 32768 ints

    // 4096 blocks x 256 threads = 2^20 threads; 16 outer iters of 4x2
    // independent float4 loads each. Fully coalesced streaming of both
    // matrices (2.147 GB total) in one kernel.
    scan_both<<<4096, 256, 0, stream>>>((const float4*)Ri, (const float4*)Ro,
                                        idx_i, idx_o);

    edge_mlp<<<(N_EDGES + 255) / 256, 256, 0, stream>>>(
        X, idx_i, idx_o, W1, b1, W2, b2, out);
}

// Round 4
// 1937.095 us; speedup vs baseline: 1.0254x; 1.0254x over previous
//
#include <hip/hip_runtime.h>
#include <math.h>

#define N_NODES 8192
#define N_EDGES 32768
#define HID 8
#define FEAT 11          // HID + 3
#define E4   (N_EDGES/4) // 8192 float4 per matrix row (power of 2)
#define UNROLL 4         // independent float4 loads per outer iter

// Native clang vector type: __builtin_nontemporal_load requires a pointer to
// scalar/native-vector, and rejects HIP_vector_type<float,4>.
typedef float nfloat4 __attribute__((ext_vector_type(4)));

// Scan one dense one-hot incidence matrix [N_NODES, N_EDGES] (row-major) and
// recover the per-column node index. Exactly one nonzero per column, so the
// plain (non-atomic) store is race-free.
//
// Single-stream per kernel (best DRAM page locality), UNROLL independent
// grid-strided float4 loads in flight, and non-temporal loads: the 1.07 GB
// stream is touched exactly once, so bypassing L2/LLC retention avoids
// evicting anything useful and can slightly raise streaming BW.
__global__ void scan_incidence(const nfloat4* __restrict__ mat,
                               int* __restrict__ idx) {
    const long total4   = (long)N_NODES * E4;            // 2^24 float4
    const long nthreads = (long)gridDim.x * blockDim.x;  // 2^20
    const long j0 = (long)blockIdx.x * blockDim.x + threadIdx.x;

    // total4 (2^24) is an exact multiple of nthreads*UNROLL (2^22): no tail.
    for (long base = j0; base < total4; base += nthreads * UNROLL) {
        nfloat4 v[UNROLL];
#pragma unroll
        for (int k = 0; k < UNROLL; ++k) {
            v[k] = __builtin_nontemporal_load(&mat[base + (long)k * nthreads]);
        }
#pragma unroll
        for (int k = 0; k < UNROLL; ++k) {
            long j = base + (long)k * nthreads;
            int n = (int)(j >> 13);              // row = j / E4 (E4 = 2^13)
            int e = (((int)j) & (E4 - 1)) << 2;  // col = (j % E4) * 4
            if (v[k].x != 0.0f) idx[e + 0] = n;
            if (v[k].y != 0.0f) idx[e + 1] = n;
            if (v[k].z != 0.0f) idx[e + 2] = n;
            if (v[k].w != 0.0f) idx[e + 3] = n;
        }
    }
}

// Per-edge: gather both endpoint feature rows, run the 2-layer MLP.
// B = [X[idx_o[e]], X[idx_i[e]]] (bo first, bi second, matching the
// reference's concatenate([bo, bi])), h = tanh(B @ W1 + b1),
// out = sigmoid(h @ W2 + b2).
__global__ void edge_mlp(const float* __restrict__ X,
                         const int*   __restrict__ idx_i,
                         const int*   __restrict__ idx_o,
                         const float* __restrict__ W1,  // [2*FEAT, HID]
                         const float* __restrict__ b1,  // [HID]
                         const float* __restrict__ W2,  // [HID]
                         const float* __restrict__ b2,  // [1]
                         float* __restrict__ out) {
    int e = blockIdx.x * blockDim.x + threadIdx.x;
    if (e >= N_EDGES) return;

    const float* xo = X + (long)idx_o[e] * FEAT;
    const float* xi = X + (long)idx_i[e] * FEAT;

    float h[HID];
#pragma unroll
    for (int j = 0; j < HID; ++j) h[j] = b1[j];

#pragma unroll
    for (int f = 0; f < FEAT; ++f) {
        float vo = xo[f];
        float vi = xi[f];
#pragma unroll
        for (int j = 0; j < HID; ++j) {
            h[j] += vo * W1[f * HID + j] + vi * W1[(FEAT + f) * HID + j];
        }
    }

    float acc = b2[0];
#pragma unroll
    for (int j = 0; j < HID; ++j) acc += tanhf(h[j]) * W2[j];

    out[e] = 1.0f / (1.0f + expf(-acc));
}

extern "C" void kernel_launch(void* const* d_in, const int* in_sizes, int n_in,
                              void* d_out, int out_size, void* d_ws, size_t ws_size,
                              hipStream_t stream) {
    const float* X  = (const float*)d_in[0];  // [8192, 11]
    const float* Ri = (const float*)d_in[1];  // [8192, 32768]
    const float* Ro = (const float*)d_in[2];  // [8192, 32768]
    const float* W1 = (const float*)d_in[3];  // [22, 8]
    const float* b1 = (const float*)d_in[4];  // [8]
    const float* W2 = (const float*)d_in[5];  // [8]
    const float* b2 = (const float*)d_in[6];  // [1]
    float* out = (float*)d_out;               // [32768]

    int* idx_i = (int*)d_ws;           // 32768 ints (every slot written by scan)
    int* idx_o = idx_i + N_EDGES;      // 32768 ints

    // One matrix per kernel: single 1.07 GB read stream each, 2^20 threads,
    // 16 float4/thread (4 outer iters x UNROLL 4 in-flight loads).
    scan_incidence<<<4096, 256, 0, stream>>>((const nfloat4*)Ri, idx_i);
    scan_incidence<<<4096, 256, 0, stream>>>((const nfloat4*)Ro, idx_o);

    edge_mlp<<<(N_EDGES + 255) / 256, 256, 0, stream>>>(
        X, idx_i, idx_o, W1, b1, W2, b2, out);
}